// Round 1
// baseline (530950.928 us; speedup 1.0000x reference)
//
#include <hip/hip_runtime.h>

#define T_LEN 512
#define BATCH 64
#define FEATD 512
#define HID   1024
#define G4H   4096
#define WINR  16
#define WLEN  33
#define OUTD  512
#define CATD  1536
#define NBLK  256
#define NTHR  512

// ---------------- workspace layout (float offsets) ----------------
// u:     [T][B][H]      33,554,432
// hh:    [3][B][4H]        786,432   (h0@Whh^T + bih + bhh, per layer)
// s:     [B][H]             65,536   (recurrent state, carries across speakers)
// x1,x2: [B][H]             65,536 each
// chist: [16][B][F]        524,288   (context ring, slot = t & 15)
// xhist: [16][B][H]      1,048,576   (LSTM-out ring)
// bar:   1024 u32            1,024
// total = 36,111,360 floats = ~137.8 MiB  (requires ws_size >= 144,445,440 B)
static const size_t SZ_U   = (size_t)T_LEN * BATCH * HID;
static const size_t SZ_HH  = (size_t)3 * BATCH * G4H;
static const size_t SZ_S   = (size_t)BATCH * HID;
static const size_t SZ_CH  = (size_t)16 * BATCH * FEATD;
static const size_t SZ_XH  = (size_t)16 * BATCH * HID;
static const size_t OFF_U  = 0;
static const size_t OFF_HH = OFF_U + SZ_U;
static const size_t OFF_S  = OFF_HH + SZ_HH;
static const size_t OFF_X1 = OFF_S + SZ_S;
static const size_t OFF_X2 = OFF_X1 + SZ_S;
static const size_t OFF_CH = OFF_X2 + SZ_S;
static const size_t OFF_XH = OFF_CH + SZ_CH;
static const size_t OFF_BAR= OFF_XH + SZ_XH;

__device__ __forceinline__ float dot4(float4 a, float4 b) {
  return a.x * b.x + a.y * b.y + a.z * b.z + a.w * b.w;
}
__device__ __forceinline__ float sigmoidf_(float x) { return 1.0f / (1.0f + expf(-x)); }

// ---------------- two-level grid barrier (256 blocks) ----------------
// 8 arrival counters 256B apart (32 blocks each) -> global counter -> gen flag.
// Generation reads are monotone per-location (cache coherence), so relaxed
// spin loads are safe; __threadfence() gives agent-scope release/acquire for
// the inter-stage data (cross-XCD L2 non-coherence, G16).
__device__ __forceinline__ void grid_barrier(unsigned* bar) {
  __syncthreads();
  __threadfence();
  if (threadIdx.x == 0) {
    unsigned* cnt  = bar + ((blockIdx.x & 7u) << 6);
    unsigned* gcnt = bar + 512;
    unsigned* gen  = bar + 576;
    unsigned g = __hip_atomic_load(gen, __ATOMIC_ACQUIRE, __HIP_MEMORY_SCOPE_AGENT);
    unsigned a = __hip_atomic_fetch_add(cnt, 1u, __ATOMIC_ACQ_REL, __HIP_MEMORY_SCOPE_AGENT);
    if (a == 31u) {
      __hip_atomic_store(cnt, 0u, __ATOMIC_RELAXED, __HIP_MEMORY_SCOPE_AGENT);
      unsigned ga = __hip_atomic_fetch_add(gcnt, 1u, __ATOMIC_ACQ_REL, __HIP_MEMORY_SCOPE_AGENT);
      if (ga == 7u) {
        __hip_atomic_store(gcnt, 0u, __ATOMIC_RELAXED, __HIP_MEMORY_SCOPE_AGENT);
        __hip_atomic_fetch_add(gen, 1u, __ATOMIC_ACQ_REL, __HIP_MEMORY_SCOPE_AGENT);
      } else {
        while (__hip_atomic_load(gen, __ATOMIC_RELAXED, __HIP_MEMORY_SCOPE_AGENT) == g)
          __builtin_amdgcn_s_sleep(2);
      }
    } else {
      while (__hip_atomic_load(gen, __ATOMIC_RELAXED, __HIP_MEMORY_SCOPE_AGENT) == g)
        __builtin_amdgcn_s_sleep(2);
    }
  }
  __syncthreads();
  __threadfence();
}

// ---------------- one LSTM layer stage ----------------
// Block covers 4 hidden units j (wave pairs split K in half), lanes = batch.
// g[b, g*H+j] = act[b,:] . W[g*H+j,:] + hh[b, g*H+j]; gate math -> xout[b,j].
template<int K>
__device__ __forceinline__ void lstm_stage(
    const float* __restrict__ act,   // [B][K]
    const float* __restrict__ W,     // [4H][K]
    const float* __restrict__ hh,    // [B][4H] precomputed recurrent+bias term
    const float* __restrict__ c0l,   // [B][H]
    float* __restrict__ xout,        // [B][H]
    float* __restrict__ xout2,       // optional duplicate (history slot)
    float* part)                     // LDS [8][4][64]
{
  const int tid  = threadIdx.x;
  const int wv   = tid >> 6;
  const int lane = tid & 63;
  const int j    = (blockIdx.x << 2) + (wv >> 1);
  const int kh   = wv & 1;
  const int KH   = K >> 1;
  const float* ar = act + (size_t)lane * K + kh * KH;
  const float* w0 = W + (size_t)(0 * HID + j) * K + kh * KH;
  const float* w1 = W + (size_t)(1 * HID + j) * K + kh * KH;
  const float* w2 = W + (size_t)(2 * HID + j) * K + kh * KH;
  const float* w3 = W + (size_t)(3 * HID + j) * K + kh * KH;
  float ai = 0.f, af = 0.f, ag = 0.f, ao = 0.f;
  #pragma unroll 4
  for (int k = 0; k < KH; k += 4) {
    float4 a4 = *(const float4*)(ar + k);
    ai += dot4(a4, *(const float4*)(w0 + k));
    af += dot4(a4, *(const float4*)(w1 + k));
    ag += dot4(a4, *(const float4*)(w2 + k));
    ao += dot4(a4, *(const float4*)(w3 + k));
  }
  part[((wv << 2) + 0) * 64 + lane] = ai;
  part[((wv << 2) + 1) * 64 + lane] = af;
  part[((wv << 2) + 2) * 64 + lane] = ag;
  part[((wv << 2) + 3) * 64 + lane] = ao;
  __syncthreads();
  if (kh == 0) {
    const int pw = wv + 1;
    float gi = part[((wv<<2)+0)*64+lane] + part[((pw<<2)+0)*64+lane] + hh[(size_t)lane*G4H + 0*HID + j];
    float gf = part[((wv<<2)+1)*64+lane] + part[((pw<<2)+1)*64+lane] + hh[(size_t)lane*G4H + 1*HID + j];
    float gg = part[((wv<<2)+2)*64+lane] + part[((pw<<2)+2)*64+lane] + hh[(size_t)lane*G4H + 2*HID + j];
    float go = part[((wv<<2)+3)*64+lane] + part[((pw<<2)+3)*64+lane] + hh[(size_t)lane*G4H + 3*HID + j];
    float cn = sigmoidf_(gf) * c0l[(size_t)lane*HID + j] + sigmoidf_(gi) * tanhf(gg);
    float hv = sigmoidf_(go) * tanhf(cn);
    xout[(size_t)lane*HID + j] = hv;
    if (xout2) xout2[(size_t)lane*HID + j] = hv;
  }
}

// ---------------- FC head: NO consecutive outputs (b fixed per lane) ----------------
template<int NO>
__device__ __forceinline__ void fc_outputs(int tp, int b, int o0,
    const float* __restrict__ xhist, const float* __restrict__ chist,
    const float* __restrict__ Wfc, const float* __restrict__ bfc,
    float* __restrict__ outp)
{
  const int sl = tp & 15;
  const float* xr = xhist + ((size_t)sl * BATCH + b) * HID;
  const float* cr = chist + ((size_t)sl * BATCH + b) * FEATD;
  float acc[NO];
  #pragma unroll
  for (int i = 0; i < NO; ++i) acc[i] = bfc[o0 + i];
  #pragma unroll 2
  for (int k = 0; k < HID; k += 4) {
    float4 a4 = *(const float4*)(xr + k);
    #pragma unroll
    for (int i = 0; i < NO; ++i)
      acc[i] += dot4(a4, *(const float4*)(Wfc + (size_t)(o0 + i) * CATD + k));
  }
  #pragma unroll 2
  for (int k = 0; k < FEATD; k += 4) {
    float4 a4 = *(const float4*)(cr + k);
    #pragma unroll
    for (int i = 0; i < NO; ++i)
      acc[i] += dot4(a4, *(const float4*)(Wfc + (size_t)(o0 + i) * CATD + HID + k));
  }
  float* op = outp + ((size_t)tp * BATCH + b) * OUTD + o0;
  #pragma unroll
  for (int i = 0; i < NO; ++i) op[i] = fmaxf(acc[i], 0.f);
}

// ---------------- persistent per-speaker decoder ----------------
__global__ void __launch_bounds__(NTHR)
decoder_kernel(const float* __restrict__ hin, const float* __restrict__ u,
               const float* __restrict__ Wih0, const float* __restrict__ Wr,
               const float* __restrict__ Wfc, const float* __restrict__ bfc,
               const float* __restrict__ c0, const float* __restrict__ hh,
               float* __restrict__ s, float* __restrict__ x1, float* __restrict__ x2,
               float* __restrict__ chist, float* __restrict__ xhist,
               unsigned* __restrict__ bar, float* __restrict__ outp)
{
  __shared__ float s_l[HID];
  __shared__ float e_l[WLEN];
  __shared__ float a_l[WLEN];
  __shared__ float part[8 * 4 * 64];

  const int tid  = threadIdx.x;
  const int bid  = blockIdx.x;
  const int wv   = tid >> 6;
  const int lane = tid & 63;

  for (int t = 0; t < T_LEN; ++t) {
    const int slot = t & 15;
    // ---- Stage A: attention (blocks 0..63, one batch row each) ----
    //      + fused FC head for steps [t-12, t) on blocks 64..255 every 12 steps
    if (bid < BATCH) {
      const int b = bid;
      s_l[tid]        = s[(size_t)b * HID + tid];
      s_l[tid + NTHR] = s[(size_t)b * HID + tid + NTHR];
      __syncthreads();
      for (int w = wv; w < WLEN; w += 8) {   // wave per window position
        const int tau = t + w - WINR;
        float e = 0.f;                        // zero-padded window -> e = 0 (kept in softmax!)
        if (tau >= 0 && tau < T_LEN) {
          const float* up = u + ((size_t)tau * BATCH + b) * HID;
          #pragma unroll
          for (int i = 0; i < 16; ++i) {
            const int hidx = lane + (i << 6);
            e += s_l[hidx] * up[hidx];
          }
          #pragma unroll
          for (int m = 32; m; m >>= 1) e += __shfl_xor(e, m);
        }
        if (lane == 0) e_l[w] = e;
      }
      __syncthreads();
      if (tid < 64) {                         // softmax over the 33 positions
        float e = (tid < WLEN) ? e_l[tid] : -1e30f;
        float mx = e;
        #pragma unroll
        for (int m = 32; m; m >>= 1) mx = fmaxf(mx, __shfl_xor(mx, m));
        float p = (tid < WLEN) ? expf(e - mx) : 0.f;
        float sm = p;
        #pragma unroll
        for (int m = 32; m; m >>= 1) sm += __shfl_xor(sm, m);
        if (tid < WLEN) a_l[tid] = p / sm;
      }
      __syncthreads();
      {                                       // context c_t[b, f], f = tid
        float c = 0.f;
        for (int w = 0; w < WLEN; ++w) {
          const int tau = t + w - WINR;
          if (tau >= 0 && tau < T_LEN)
            c = fmaf(a_l[w], hin[((size_t)tau * BATCH + b) * FEATD + tid], c);
        }
        chist[((size_t)slot * BATCH + b) * FEATD + tid] = c;
      }
    } else if (t >= 12 && (t % 12) == 0) {
      // 192 blocks = 16 blocks x 12 timesteps; block covers 32 outputs x all b
      const int fb = bid - BATCH;
      const int tp = t - 12 + (fb >> 4);
      const int o0 = ((fb & 15) << 5) + (wv << 2);
      fc_outputs<4>(tp, lane, o0, xhist, chist, Wfc, bfc, outp);
    }
    grid_barrier(bar);
    // ---- Stage B/C/D: the three LSTM layers ----
    lstm_stage<FEATD>(chist + (size_t)slot * BATCH * FEATD, Wih0,
                      hh, c0, x1, nullptr, part);
    grid_barrier(bar);
    lstm_stage<HID>(x1, Wr, hh + (size_t)BATCH * G4H,
                    c0 + (size_t)BATCH * HID, x2, nullptr, part);
    grid_barrier(bar);
    lstm_stage<HID>(x2, Wr + (size_t)G4H * HID, hh + (size_t)2 * BATCH * G4H,
                    c0 + (size_t)2 * BATCH * HID, s,
                    xhist + (size_t)slot * BATCH * HID, part);
    grid_barrier(bar);
  }
  // ---- epilogue: FC head for the last 8 steps (504..511), all 256 blocks ----
  {
    const int tp = 504 + (bid >> 5);
    const int o0 = ((bid & 31) << 4) + (wv << 1);
    fc_outputs<2>(tp, lane, o0, xhist, chist, Wfc, bfc, outp);
  }
}

// ---------------- u = h @ Wa_sp^T : [32768,512] x [1024,512]^T ----------------
__global__ void __launch_bounds__(256)
gemm_u_kernel(const float* __restrict__ A,    // h   [32768][512]
              const float* __restrict__ Bm,   // Wa  [1024][512]
              float* __restrict__ C)          // u   [32768][1024]
{
  __shared__ float Al[64 * 68];
  __shared__ float Bl[64 * 68];
  const int tid = threadIdx.x;
  const int m0 = blockIdx.x * 64;
  const int n0 = blockIdx.y * 64;
  const int tx = tid & 15, ty = tid >> 4;
  float acc[4][4] = {};
  for (int kc = 0; kc < 512; kc += 64) {
    #pragma unroll
    for (int p = 0; p < 4; ++p) {
      const int row = p * 16 + (tid >> 4);
      const int kq  = (tid & 15) * 4;
      float4 v = *(const float4*)(A + (size_t)(m0 + row) * 512 + kc + kq);
      Al[(kq + 0) * 68 + row] = v.x;
      Al[(kq + 1) * 68 + row] = v.y;
      Al[(kq + 2) * 68 + row] = v.z;
      Al[(kq + 3) * 68 + row] = v.w;
      float4 w = *(const float4*)(Bm + (size_t)(n0 + row) * 512 + kc + kq);
      Bl[(kq + 0) * 68 + row] = w.x;
      Bl[(kq + 1) * 68 + row] = w.y;
      Bl[(kq + 2) * 68 + row] = w.z;
      Bl[(kq + 3) * 68 + row] = w.w;
    }
    __syncthreads();
    #pragma unroll 8
    for (int k = 0; k < 64; ++k) {
      float4 av = *(const float4*)(&Al[k * 68 + ty * 4]);
      float4 bv = *(const float4*)(&Bl[k * 68 + tx * 4]);
      float aa[4] = {av.x, av.y, av.z, av.w};
      float bb[4] = {bv.x, bv.y, bv.z, bv.w};
      #pragma unroll
      for (int i = 0; i < 4; ++i)
        #pragma unroll
        for (int jj = 0; jj < 4; ++jj)
          acc[i][jj] = fmaf(aa[i], bb[jj], acc[i][jj]);
    }
    __syncthreads();
  }
  #pragma unroll
  for (int i = 0; i < 4; ++i) {
    float4 r = {acc[i][0], acc[i][1], acc[i][2], acc[i][3]};
    *(float4*)(C + (size_t)(m0 + ty * 4 + i) * 1024 + n0 + tx * 4) = r;
  }
}

// ---------------- hh[l,b,n] = h0[l,b,:] . Whh_l[n,:] + bih_l[n] + bhh_l[n] ----------------
__global__ void __launch_bounds__(256)
hhconst_kernel(const float* __restrict__ Whh0, const float* __restrict__ Whr,
               const float* __restrict__ bih0, const float* __restrict__ bhh0,
               const float* __restrict__ bihr, const float* __restrict__ bhhr,
               const float* __restrict__ h0, float* __restrict__ hh)
{
  const int idx = blockIdx.x * 256 + threadIdx.x;   // 786432 total
  const int b = idx & 63;
  const int n = (idx >> 6) & 4095;
  const int l = idx >> 18;
  const float* W = (l == 0) ? (Whh0 + (size_t)n * HID)
                            : (Whr + ((size_t)(l - 1) * G4H + n) * HID);
  float acc = ((l == 0) ? bih0[n] : bihr[(l - 1) * G4H + n])
            + ((l == 0) ? bhh0[n] : bhhr[(l - 1) * G4H + n]);
  const float* hr = h0 + ((size_t)l * BATCH + b) * HID;
  #pragma unroll 2
  for (int k = 0; k < HID; k += 4)
    acc += dot4(*(const float4*)(hr + k), *(const float4*)(W + k));
  hh[((size_t)l * BATCH + b) * G4H + n] = acc;
}

__global__ void __launch_bounds__(256)
init_kernel(const float* __restrict__ s0, float* __restrict__ s, unsigned* __restrict__ bar)
{
  const int gid = blockIdx.x * 256 + threadIdx.x;
  if (gid < BATCH * HID) s[gid] = s0[gid];
  if (blockIdx.x == 0)
    for (int i = threadIdx.x; i < 1024; i += 256) bar[i] = 0u;
}

extern "C" void kernel_launch(void* const* d_in, const int* in_sizes, int n_in,
                              void* d_out, int out_size, void* d_ws, size_t ws_size,
                              hipStream_t stream) {
  (void)in_sizes; (void)n_in; (void)out_size; (void)ws_size;
  const float* h    = (const float*)d_in[0];
  const float* Wa   = (const float*)d_in[1];
  const float* Wih0 = (const float*)d_in[2];
  const float* Whh0 = (const float*)d_in[3];
  const float* bih0 = (const float*)d_in[4];
  const float* bhh0 = (const float*)d_in[5];
  const float* Wihr = (const float*)d_in[6];
  const float* Whhr = (const float*)d_in[7];
  const float* bihr = (const float*)d_in[8];
  const float* bhhr = (const float*)d_in[9];
  const float* Wfc  = (const float*)d_in[10];
  const float* bfc  = (const float*)d_in[11];
  const float* s0   = (const float*)d_in[12];
  const float* h0   = (const float*)d_in[13];
  const float* c0   = (const float*)d_in[14];
  float* out = (float*)d_out;
  float* ws  = (float*)d_ws;

  float* u      = ws + OFF_U;
  float* hh     = ws + OFF_HH;
  float* s      = ws + OFF_S;
  float* x1     = ws + OFF_X1;
  float* x2     = ws + OFF_X2;
  float* chist  = ws + OFF_CH;
  float* xhist  = ws + OFF_XH;
  unsigned* bar = (unsigned*)(ws + OFF_BAR);

  hipLaunchKernelGGL(init_kernel, dim3(256), dim3(256), 0, stream, s0, s, bar);
  hipLaunchKernelGGL(hhconst_kernel, dim3(3072), dim3(256), 0, stream,
                     Whh0, Whhr, bih0, bhh0, bihr, bhhr, h0, hh);
  for (int sp = 0; sp < 2; ++sp) {
    hipLaunchKernelGGL(gemm_u_kernel, dim3(512, 16), dim3(256), 0, stream,
                       h, Wa + (size_t)sp * HID * FEATD, u);
    hipLaunchKernelGGL(decoder_kernel, dim3(NBLK), dim3(NTHR), 0, stream,
                       h, u, Wih0, Wihr, Wfc, bfc, c0, hh, s, x1, x2,
                       chist, xhist, bar,
                       out + (size_t)sp * T_LEN * BATCH * OUTD);
  }
}

// Round 2
// 453214.941 us; speedup vs baseline: 1.1715x; 1.1715x over previous
//
#include <hip/hip_runtime.h>

#define T_LEN 512
#define BATCH 64
#define FEATD 512
#define HID   1024
#define G4H   4096
#define WINR  16
#define WLEN  33
#define OUTD  512
#define CATD  1536
#define NBLK  256
#define NTHR  512

// ---------------- workspace layout (float offsets) ----------------
// u:      [T][B][H]      33,554,432
// hhT:    [3][4H][B]        786,432   (h0@Whh^T + bih + bhh, k-major)
// s:      [B][H]             65,536   (b-major: attention reads rows)
// x1T,x2T:[H][B]             65,536 each  (k-major: LSTM stages read coalesced)
// chistT: [16][F][B]        524,288   (context ring, k-major)
// xhistT: [16][H][B]      1,048,576   (LSTM-out ring, k-major)
// bar:    1024 u32            1,024
static const size_t SZ_U   = (size_t)T_LEN * BATCH * HID;
static const size_t SZ_HH  = (size_t)3 * BATCH * G4H;
static const size_t SZ_S   = (size_t)BATCH * HID;
static const size_t SZ_CH  = (size_t)16 * BATCH * FEATD;
static const size_t SZ_XH  = (size_t)16 * BATCH * HID;
static const size_t OFF_U  = 0;
static const size_t OFF_HH = OFF_U + SZ_U;
static const size_t OFF_S  = OFF_HH + SZ_HH;
static const size_t OFF_X1 = OFF_S + SZ_S;
static const size_t OFF_X2 = OFF_X1 + SZ_S;
static const size_t OFF_CH = OFF_X2 + SZ_S;
static const size_t OFF_XH = OFF_CH + SZ_CH;
static const size_t OFF_BAR= OFF_XH + SZ_XH;

__device__ __forceinline__ float sigmoidf_(float x) { return 1.0f / (1.0f + expf(-x)); }

// ---------------- two-level grid barrier (256 blocks) ----------------
__device__ __forceinline__ void grid_barrier(unsigned* bar) {
  __syncthreads();
  __threadfence();
  if (threadIdx.x == 0) {
    unsigned* cnt  = bar + ((blockIdx.x & 7u) << 6);
    unsigned* gcnt = bar + 512;
    unsigned* gen  = bar + 576;
    unsigned g = __hip_atomic_load(gen, __ATOMIC_ACQUIRE, __HIP_MEMORY_SCOPE_AGENT);
    unsigned a = __hip_atomic_fetch_add(cnt, 1u, __ATOMIC_ACQ_REL, __HIP_MEMORY_SCOPE_AGENT);
    if (a == 31u) {
      __hip_atomic_store(cnt, 0u, __ATOMIC_RELAXED, __HIP_MEMORY_SCOPE_AGENT);
      unsigned ga = __hip_atomic_fetch_add(gcnt, 1u, __ATOMIC_ACQ_REL, __HIP_MEMORY_SCOPE_AGENT);
      if (ga == 7u) {
        __hip_atomic_store(gcnt, 0u, __ATOMIC_RELAXED, __HIP_MEMORY_SCOPE_AGENT);
        __hip_atomic_fetch_add(gen, 1u, __ATOMIC_ACQ_REL, __HIP_MEMORY_SCOPE_AGENT);
      } else {
        while (__hip_atomic_load(gen, __ATOMIC_RELAXED, __HIP_MEMORY_SCOPE_AGENT) == g)
          __builtin_amdgcn_s_sleep(2);
      }
    } else {
      while (__hip_atomic_load(gen, __ATOMIC_RELAXED, __HIP_MEMORY_SCOPE_AGENT) == g)
        __builtin_amdgcn_s_sleep(2);
    }
  }
  __syncthreads();
  __threadfence();
}

// ---------------- one LSTM layer stage (k-major activations) ----------------
// Block covers 4 hidden units j. Wave wv: jl = wv>>1 selects j, gp = wv&1
// selects gate pair {i,f} or {g,o}. Lanes = batch (coalesced act reads).
template<int K>
__device__ __forceinline__ void lstm_stage(
    const float* __restrict__ actT,  // [K][64] k-major
    const float* __restrict__ W,     // [4H][K] row-major
    const float* __restrict__ hhT,   // [4H][64] k-major precomputed term
    const float* __restrict__ c0l,   // [B][H] b-major (1 scattered load/wave)
    float* __restrict__ xoutT,       // [H][64] k-major
    float* __restrict__ xout2T,      // optional duplicate (history slot)
    float* __restrict__ sOut,        // optional [B][H] b-major (attention input)
    float* part)                     // LDS [4][4][64]
{
  const int tid  = threadIdx.x;
  const int wv   = tid >> 6;
  const int lane = tid & 63;
  const int jl   = wv >> 1;
  const int gp   = wv & 1;
  const int j    = (blockIdx.x << 2) + jl;
  const int n0   = (2 * gp) * HID + j;
  const int n1   = (2 * gp + 1) * HID + j;
  const float* w0 = W + (size_t)n0 * K;
  const float* w1 = W + (size_t)n1 * K;
  const float* ap = actT + lane;
  float a0 = 0.f, a1 = 0.f;
  for (int k = 0; k < K; k += 16) {
    alignas(16) float w0r[16], w1r[16];
    *(float4*)&w0r[0]  = *(const float4*)(w0 + k + 0);
    *(float4*)&w0r[4]  = *(const float4*)(w0 + k + 4);
    *(float4*)&w0r[8]  = *(const float4*)(w0 + k + 8);
    *(float4*)&w0r[12] = *(const float4*)(w0 + k + 12);
    *(float4*)&w1r[0]  = *(const float4*)(w1 + k + 0);
    *(float4*)&w1r[4]  = *(const float4*)(w1 + k + 4);
    *(float4*)&w1r[8]  = *(const float4*)(w1 + k + 8);
    *(float4*)&w1r[12] = *(const float4*)(w1 + k + 12);
    float av[16];
    #pragma unroll
    for (int kk = 0; kk < 16; ++kk) av[kk] = ap[(size_t)(k + kk) * 64];
    #pragma unroll
    for (int kk = 0; kk < 16; ++kk) {
      a0 = fmaf(av[kk], w0r[kk], a0);
      a1 = fmaf(av[kk], w1r[kk], a1);
    }
  }
  part[((jl << 2) + 2 * gp + 0) * 64 + lane] = a0 + hhT[(size_t)n0 * 64 + lane];
  part[((jl << 2) + 2 * gp + 1) * 64 + lane] = a1 + hhT[(size_t)n1 * 64 + lane];
  __syncthreads();
  if (gp == 0) {
    float gi = part[((jl << 2) + 0) * 64 + lane];
    float gf = part[((jl << 2) + 1) * 64 + lane];
    float gg = part[((jl << 2) + 2) * 64 + lane];
    float go = part[((jl << 2) + 3) * 64 + lane];
    float cn = sigmoidf_(gf) * c0l[(size_t)lane * HID + j] + sigmoidf_(gi) * tanhf(gg);
    float hv = sigmoidf_(go) * tanhf(cn);
    xoutT[(size_t)j * 64 + lane] = hv;
    if (xout2T) xout2T[(size_t)j * 64 + lane] = hv;
    if (sOut)   sOut[(size_t)lane * HID + j]  = hv;
  }
}

// ---------------- FC head (k-major history reads) ----------------
template<int NO>
__device__ __forceinline__ void fc_outputs(int tp, int o0,
    const float* __restrict__ xhistT, const float* __restrict__ chistT,
    const float* __restrict__ Wfc, const float* __restrict__ bfc,
    float* __restrict__ outp)
{
  const int lane = threadIdx.x & 63;   // = b
  const int sl = tp & 15;
  const float* xr = xhistT + (size_t)sl * HID * 64 + lane;
  const float* cr = chistT + (size_t)sl * FEATD * 64 + lane;
  float acc[NO];
  #pragma unroll
  for (int i = 0; i < NO; ++i) acc[i] = bfc[o0 + i];
  for (int k = 0; k < HID; k += 4) {
    float a0 = xr[(size_t)(k + 0) * 64];
    float a1 = xr[(size_t)(k + 1) * 64];
    float a2 = xr[(size_t)(k + 2) * 64];
    float a3 = xr[(size_t)(k + 3) * 64];
    #pragma unroll
    for (int i = 0; i < NO; ++i) {
      float4 w = *(const float4*)(Wfc + (size_t)(o0 + i) * CATD + k);
      acc[i] = fmaf(a0, w.x, fmaf(a1, w.y, fmaf(a2, w.z, fmaf(a3, w.w, acc[i]))));
    }
  }
  for (int k = 0; k < FEATD; k += 4) {
    float a0 = cr[(size_t)(k + 0) * 64];
    float a1 = cr[(size_t)(k + 1) * 64];
    float a2 = cr[(size_t)(k + 2) * 64];
    float a3 = cr[(size_t)(k + 3) * 64];
    #pragma unroll
    for (int i = 0; i < NO; ++i) {
      float4 w = *(const float4*)(Wfc + (size_t)(o0 + i) * CATD + HID + k);
      acc[i] = fmaf(a0, w.x, fmaf(a1, w.y, fmaf(a2, w.z, fmaf(a3, w.w, acc[i]))));
    }
  }
  float* op = outp + ((size_t)tp * BATCH + lane) * OUTD + o0;
  #pragma unroll
  for (int i = 0; i < NO; ++i) op[i] = fmaxf(acc[i], 0.f);
}

// ---------------- persistent per-speaker decoder ----------------
__global__ void __launch_bounds__(NTHR)
decoder_kernel(const float* __restrict__ hin, const float* __restrict__ u,
               const float* __restrict__ Wih0, const float* __restrict__ Wr,
               const float* __restrict__ Wfc, const float* __restrict__ bfc,
               const float* __restrict__ c0, const float* __restrict__ hhT,
               float* __restrict__ s, float* __restrict__ x1T, float* __restrict__ x2T,
               float* __restrict__ chistT, float* __restrict__ xhistT,
               unsigned* __restrict__ bar, float* __restrict__ outp)
{
  __shared__ float s_l[HID];
  __shared__ float e_l[WLEN];
  __shared__ float a_l[WLEN];
  __shared__ float part[4 * 4 * 64];

  const int tid  = threadIdx.x;
  const int bid  = blockIdx.x;
  const int wv   = tid >> 6;
  const int lane = tid & 63;

  for (int t = 0; t < T_LEN; ++t) {
    const int slot = t & 15;
    // ---- Stage A: attention (blocks 0..63) + FC head chunks (blocks 64..255) ----
    if (bid < BATCH) {
      const int b = bid;
      s_l[tid]        = s[(size_t)b * HID + tid];
      s_l[tid + NTHR] = s[(size_t)b * HID + tid + NTHR];
      __syncthreads();
      for (int w = wv; w < WLEN; w += 8) {
        const int tau = t + w - WINR;
        float e = 0.f;   // zero-padded window -> e = 0 (participates in softmax!)
        if (tau >= 0 && tau < T_LEN) {
          const float* up = u + ((size_t)tau * BATCH + b) * HID;
          #pragma unroll
          for (int i = 0; i < 16; ++i) {
            const int hidx = lane + (i << 6);
            e += s_l[hidx] * up[hidx];
          }
          #pragma unroll
          for (int m = 32; m; m >>= 1) e += __shfl_xor(e, m);
        }
        if (lane == 0) e_l[w] = e;
      }
      __syncthreads();
      if (tid < 64) {
        float e = (tid < WLEN) ? e_l[tid] : -1e30f;
        float mx = e;
        #pragma unroll
        for (int m = 32; m; m >>= 1) mx = fmaxf(mx, __shfl_xor(mx, m));
        float p = (tid < WLEN) ? expf(e - mx) : 0.f;
        float sm = p;
        #pragma unroll
        for (int m = 32; m; m >>= 1) sm += __shfl_xor(sm, m);
        if (tid < WLEN) a_l[tid] = p / sm;
      }
      __syncthreads();
      {
        float c = 0.f;
        for (int w = 0; w < WLEN; ++w) {
          const int tau = t + w - WINR;
          if (tau >= 0 && tau < T_LEN)
            c = fmaf(a_l[w], hin[((size_t)tau * BATCH + b) * FEATD + tid], c);
        }
        chistT[((size_t)slot * FEATD + tid) * 64 + b] = c;   // k-major store
      }
    } else if (t >= 12 && (t % 12) == 0) {
      const int fb = bid - BATCH;
      const int tp = t - 12 + (fb >> 4);
      const int o0 = ((fb & 15) << 5) + (wv << 2);
      fc_outputs<4>(tp, o0, xhistT, chistT, Wfc, bfc, outp);
    }
    grid_barrier(bar);
    // ---- Stages B/C/D: the three LSTM layers ----
    lstm_stage<FEATD>(chistT + (size_t)slot * FEATD * 64, Wih0,
                      hhT, c0, x1T, nullptr, nullptr, part);
    grid_barrier(bar);
    lstm_stage<HID>(x1T, Wr, hhT + (size_t)G4H * 64,
                    c0 + (size_t)BATCH * HID, x2T, nullptr, nullptr, part);
    grid_barrier(bar);
    lstm_stage<HID>(x2T, Wr + (size_t)G4H * HID, hhT + (size_t)2 * G4H * 64,
                    c0 + (size_t)2 * BATCH * HID,
                    xhistT + (size_t)slot * HID * 64, nullptr, s, part);
    grid_barrier(bar);
  }
  // ---- epilogue: FC head for steps 504..511, all 256 blocks ----
  {
    const int tp = 504 + (bid >> 5);
    const int o0 = ((bid & 31) << 4) + (wv << 1);
    fc_outputs<2>(tp, o0, xhistT, chistT, Wfc, bfc, outp);
  }
}

// ---------------- u = h @ Wa_sp^T : [32768,512] x [1024,512]^T ----------------
__global__ void __launch_bounds__(256)
gemm_u_kernel(const float* __restrict__ A,    // h   [32768][512]
              const float* __restrict__ Bm,   // Wa  [1024][512]
              float* __restrict__ C)          // u   [32768][1024]
{
  __shared__ float Al[64 * 68];
  __shared__ float Bl[64 * 68];
  const int tid = threadIdx.x;
  const int m0 = blockIdx.x * 64;
  const int n0 = blockIdx.y * 64;
  const int tx = tid & 15, ty = tid >> 4;
  float acc[4][4] = {};
  for (int kc = 0; kc < 512; kc += 64) {
    #pragma unroll
    for (int p = 0; p < 4; ++p) {
      const int row = p * 16 + (tid >> 4);
      const int kq  = (tid & 15) * 4;
      float4 v = *(const float4*)(A + (size_t)(m0 + row) * 512 + kc + kq);
      Al[(kq + 0) * 68 + row] = v.x;
      Al[(kq + 1) * 68 + row] = v.y;
      Al[(kq + 2) * 68 + row] = v.z;
      Al[(kq + 3) * 68 + row] = v.w;
      float4 w = *(const float4*)(Bm + (size_t)(n0 + row) * 512 + kc + kq);
      Bl[(kq + 0) * 68 + row] = w.x;
      Bl[(kq + 1) * 68 + row] = w.y;
      Bl[(kq + 2) * 68 + row] = w.z;
      Bl[(kq + 3) * 68 + row] = w.w;
    }
    __syncthreads();
    #pragma unroll 8
    for (int k = 0; k < 64; ++k) {
      float4 av = *(const float4*)(&Al[k * 68 + ty * 4]);
      float4 bv = *(const float4*)(&Bl[k * 68 + tx * 4]);
      float aa[4] = {av.x, av.y, av.z, av.w};
      float bb[4] = {bv.x, bv.y, bv.z, bv.w};
      #pragma unroll
      for (int i = 0; i < 4; ++i)
        #pragma unroll
        for (int jj = 0; jj < 4; ++jj)
          acc[i][jj] = fmaf(aa[i], bb[jj], acc[i][jj]);
    }
    __syncthreads();
  }
  #pragma unroll
  for (int i = 0; i < 4; ++i) {
    float4 r = {acc[i][0], acc[i][1], acc[i][2], acc[i][3]};
    *(float4*)(C + (size_t)(m0 + ty * 4 + i) * 1024 + n0 + tx * 4) = r;
  }
}

// ------- hhT[l][n][b] = h0[l,b,:] . Whh_l[n,:] + bih_l[n] + bhh_l[n] -------
__global__ void __launch_bounds__(256)
hhconst_kernel(const float* __restrict__ Whh0, const float* __restrict__ Whr,
               const float* __restrict__ bih0, const float* __restrict__ bhh0,
               const float* __restrict__ bihr, const float* __restrict__ bhhr,
               const float* __restrict__ h0, float* __restrict__ hh)
{
  const int idx = blockIdx.x * 256 + threadIdx.x;   // 786432 total
  const int b = idx & 63;
  const int n = (idx >> 6) & 4095;
  const int l = idx >> 18;
  const float* W = (l == 0) ? (Whh0 + (size_t)n * HID)
                            : (Whr + ((size_t)(l - 1) * G4H + n) * HID);
  float acc = ((l == 0) ? bih0[n] : bihr[(l - 1) * G4H + n])
            + ((l == 0) ? bhh0[n] : bhhr[(l - 1) * G4H + n]);
  const float* hr = h0 + ((size_t)l * BATCH + b) * HID;
  #pragma unroll 2
  for (int k = 0; k < HID; k += 4) {
    float4 a4 = *(const float4*)(hr + k);
    float4 w4 = *(const float4*)(W + k);
    acc += a4.x * w4.x + a4.y * w4.y + a4.z * w4.z + a4.w * w4.w;
  }
  hh[idx] = acc;    // idx == (l*G4H + n)*64 + b  -> k-major layout, coalesced
}

__global__ void __launch_bounds__(256)
init_kernel(const float* __restrict__ s0, float* __restrict__ s, unsigned* __restrict__ bar)
{
  const int gid = blockIdx.x * 256 + threadIdx.x;
  if (gid < BATCH * HID) s[gid] = s0[gid];
  if (blockIdx.x == 0)
    for (int i = threadIdx.x; i < 1024; i += 256) bar[i] = 0u;
}

extern "C" void kernel_launch(void* const* d_in, const int* in_sizes, int n_in,
                              void* d_out, int out_size, void* d_ws, size_t ws_size,
                              hipStream_t stream) {
  (void)in_sizes; (void)n_in; (void)out_size; (void)ws_size;
  const float* h    = (const float*)d_in[0];
  const float* Wa   = (const float*)d_in[1];
  const float* Wih0 = (const float*)d_in[2];
  const float* Whh0 = (const float*)d_in[3];
  const float* bih0 = (const float*)d_in[4];
  const float* bhh0 = (const float*)d_in[5];
  const float* Wihr = (const float*)d_in[6];
  const float* Whhr = (const float*)d_in[7];
  const float* bihr = (const float*)d_in[8];
  const float* bhhr = (const float*)d_in[9];
  const float* Wfc  = (const float*)d_in[10];
  const float* bfc  = (const float*)d_in[11];
  const float* s0   = (const float*)d_in[12];
  const float* h0   = (const float*)d_in[13];
  const float* c0   = (const float*)d_in[14];
  float* out = (float*)d_out;
  float* ws  = (float*)d_ws;

  float* u      = ws + OFF_U;
  float* hhT    = ws + OFF_HH;
  float* s      = ws + OFF_S;
  float* x1T    = ws + OFF_X1;
  float* x2T    = ws + OFF_X2;
  float* chistT = ws + OFF_CH;
  float* xhistT = ws + OFF_XH;
  unsigned* bar = (unsigned*)(ws + OFF_BAR);

  hipLaunchKernelGGL(init_kernel, dim3(256), dim3(256), 0, stream, s0, s, bar);
  hipLaunchKernelGGL(hhconst_kernel, dim3(3072), dim3(256), 0, stream,
                     Whh0, Whhr, bih0, bhh0, bihr, bhhr, h0, hhT);
  for (int sp = 0; sp < 2; ++sp) {
    hipLaunchKernelGGL(gemm_u_kernel, dim3(512, 16), dim3(256), 0, stream,
                       h, Wa + (size_t)sp * HID * FEATD, u);
    hipLaunchKernelGGL(decoder_kernel, dim3(NBLK), dim3(NTHR), 0, stream,
                       h, u, Wih0, Wihr, Wfc, bfc, c0, hhT, s, x1T, x2T,
                       chistT, xhistT, bar,
                       out + (size_t)sp * T_LEN * BATCH * OUTD);
  }
}

// Round 3
// 326757.300 us; speedup vs baseline: 1.6249x; 1.3870x over previous
//
#include <hip/hip_runtime.h>

#define T_LEN 512
#define BATCH 64
#define FEATD 512
#define HID   1024
#define G4H   4096
#define WINR  16
#define WLEN  33
#define OUTD  512
#define CATD  1536
#define NBLK  256
#define NTHR  512

typedef unsigned int uint32;
typedef unsigned short ushort16;
typedef short s16x8 __attribute__((ext_vector_type(8)));
typedef float f32x4 __attribute__((ext_vector_type(4)));

// ---------------- workspace layout (float offsets) ----------------
// u:      [T][B][H] fp32                33,554,432
// hhT:    [3][4H][B] fp32                  786,432
// s:      [B][H] fp32                       65,536
// cB4:    [F/4][64][4] bf16   32768 sh ->   16,384
// x1B4:   [H/4][64][4] bf16   65536 sh ->   32,768
// x2B4:   [H/4][64][4] bf16   65536 sh ->   32,768
// chistK: [16][F][64] bf16  524288 sh ->   262,144
// xhistK: [16][H][64] bf16 1048576 sh ->   524,288
// bar:    1024 u32                           1,024
// total 35,275,776 floats = 141.1 MB
static const size_t OFF_U   = 0;
static const size_t OFF_HH  = 33554432;
static const size_t OFF_S   = OFF_HH + 786432;
static const size_t OFF_CB  = OFF_S  + 65536;
static const size_t OFF_X1  = OFF_CB + 16384;
static const size_t OFF_X2  = OFF_X1 + 32768;
static const size_t OFF_CK  = OFF_X2 + 32768;
static const size_t OFF_XK  = OFF_CK + 262144;
static const size_t OFF_BAR = OFF_XK + 524288;

__device__ __forceinline__ float sigmoidf_(float x) { return 1.0f / (1.0f + expf(-x)); }
__device__ __forceinline__ ushort16 f2bf(float f) {
  uint32 u = __float_as_uint(f);
  uint32 r = u + 0x7FFFu + ((u >> 16) & 1u);   // RNE
  return (ushort16)(r >> 16);
}
__device__ __forceinline__ float bf2f(ushort16 u) {
  return __uint_as_float(((uint32)u) << 16);
}

// ---------------- two-level grid barrier (256 blocks) ----------------
__device__ __forceinline__ void grid_barrier(unsigned* bar) {
  __syncthreads();
  __threadfence();
  if (threadIdx.x == 0) {
    unsigned* cnt  = bar + ((blockIdx.x & 7u) << 6);
    unsigned* gcnt = bar + 512;
    unsigned* gen  = bar + 576;
    unsigned g = __hip_atomic_load(gen, __ATOMIC_ACQUIRE, __HIP_MEMORY_SCOPE_AGENT);
    unsigned a = __hip_atomic_fetch_add(cnt, 1u, __ATOMIC_ACQ_REL, __HIP_MEMORY_SCOPE_AGENT);
    if (a == 31u) {
      __hip_atomic_store(cnt, 0u, __ATOMIC_RELAXED, __HIP_MEMORY_SCOPE_AGENT);
      unsigned ga = __hip_atomic_fetch_add(gcnt, 1u, __ATOMIC_ACQ_REL, __HIP_MEMORY_SCOPE_AGENT);
      if (ga == 7u) {
        __hip_atomic_store(gcnt, 0u, __ATOMIC_RELAXED, __HIP_MEMORY_SCOPE_AGENT);
        __hip_atomic_fetch_add(gen, 1u, __ATOMIC_ACQ_REL, __HIP_MEMORY_SCOPE_AGENT);
      } else {
        while (__hip_atomic_load(gen, __ATOMIC_RELAXED, __HIP_MEMORY_SCOPE_AGENT) == g)
          __builtin_amdgcn_s_sleep(1);
      }
    } else {
      while (__hip_atomic_load(gen, __ATOMIC_RELAXED, __HIP_MEMORY_SCOPE_AGENT) == g)
        __builtin_amdgcn_s_sleep(1);
    }
  }
  __syncthreads();
  __threadfence();
}

// ---------------- MFMA LSTM stage ----------------
// Block owns 16 W-rows: m = gate*4 + jl, row n = gate*HID + blockIdx*4 + jl.
// A-frags (bf16) pre-swizzled in LDS: wl[ks][lane][8], k = ks*32 + quad*8 + j.
// B-frags from global actB4 [K/4][64][4] bf16 (b-major groups of 4 k).
// Waves: nt = wv&3 (N-tile of 16 b), kh = wv>>2 (K-half). LDS-reduce, gate math.
template<int KSTEPS>
__device__ __forceinline__ void lstm_stage_mfma(
    const ushort16* __restrict__ wl,     // LDS [KSTEPS][64][8]
    const ushort16* __restrict__ actB4,  // global [K/4][64][4]
    const float* __restrict__ hhT,       // [4H][64] (this layer)
    const float* __restrict__ c0l,       // [B][HID] b-major (this layer)
    ushort16* __restrict__ xoutB4,       // next act [H/4][64][4] or null
    ushort16* __restrict__ xhistK_slot,  // [H][64] or null
    float* __restrict__ sOut,            // [B][HID] or null
    float* __restrict__ red)             // LDS [2][4][16][16]
{
  const int tid  = threadIdx.x;
  const int wv   = tid >> 6;
  const int lane = tid & 63;
  const int nt   = wv & 3;
  const int kh   = wv >> 2;
  const int quad = lane >> 4;
  const int b    = nt * 16 + (lane & 15);
  const int half = KSTEPS / 2;

  f32x4 acc = {0.f, 0.f, 0.f, 0.f};
  #pragma unroll 4
  for (int i = 0; i < half; ++i) {
    const int ks = kh * half + i;
    s16x8 afrag = *(const s16x8*)(wl + ((size_t)ks * 64 + lane) * 8);
    const int g0 = ks * 8 + quad * 2;
    uint2 lo = *(const uint2*)(actB4 + ((size_t)g0 * 64 + b) * 4);
    uint2 hi = *(const uint2*)(actB4 + ((size_t)(g0 + 1) * 64 + b) * 4);
    union { uint4 u; s16x8 v; } bf;
    bf.u = make_uint4(lo.x, lo.y, hi.x, hi.y);
    acc = __builtin_amdgcn_mfma_f32_16x16x32_bf16(afrag, bf.v, acc, 0, 0, 0);
  }
  // partials: C-layout col=lane&15, row=quad*4+reg
  {
    float* rp = red + (((size_t)(kh * 4 + nt) * 16 + quad * 4) * 16) + (lane & 15);
    rp[0]  = acc[0];
    rp[16] = acc[1];
    rp[32] = acc[2];
    rp[48] = acc[3];
  }
  __syncthreads();
  if (wv < 4) {
    const int jl = wv;
    const int bb = lane;
    const int ntb = bb >> 4, col = bb & 15;
    const int j = (blockIdx.x << 2) + jl;
    float g[4];
    #pragma unroll
    for (int gate = 0; gate < 4; ++gate) {
      const int m = gate * 4 + jl;
      g[gate] = red[((size_t)(0 + ntb) * 16 + m) * 16 + col]
              + red[((size_t)(4 + ntb) * 16 + m) * 16 + col]
              + hhT[((size_t)gate * HID + j) * 64 + bb];
    }
    float cn = sigmoidf_(g[1]) * c0l[(size_t)bb * HID + j] + sigmoidf_(g[0]) * tanhf(g[2]);
    float hv = sigmoidf_(g[3]) * tanhf(cn);
    ushort16 hb = f2bf(hv);
    if (xoutB4)      xoutB4[((size_t)blockIdx.x * 64 + bb) * 4 + jl] = hb;  // group j>>2 == blockIdx
    if (xhistK_slot) xhistK_slot[(size_t)j * 64 + bb] = hb;                 // coalesced
    if (sOut)        sOut[(size_t)bb * HID + j] = hv;                       // scatter (small)
  }
}

// ---------------- FC head: one output per wave, coalesced k-major reads ----------------
__device__ __forceinline__ void fc_step(int tp, int obase,
    const ushort16* __restrict__ chistK, const ushort16* __restrict__ xhistK,
    const float* __restrict__ Wfc, const float* __restrict__ bfc,
    float* __restrict__ outp, float* __restrict__ fcl)
{
  const int tid = threadIdx.x, wv = tid >> 6, lane = tid & 63;
  const int slot = tp & 15;
  const int o = obase + wv;
  const ushort16* xr = xhistK + (size_t)slot * HID * 64 + lane;
  const ushort16* cr = chistK + (size_t)slot * FEATD * 64 + lane;
  const float* wr = Wfc + (size_t)o * CATD;
  float acc = bfc[o];
  #pragma unroll 2
  for (int k = 0; k < HID; k += 4) {
    float4 w = *(const float4*)(wr + k);
    acc = fmaf(bf2f(xr[(size_t)(k + 0) * 64]), w.x, acc);
    acc = fmaf(bf2f(xr[(size_t)(k + 1) * 64]), w.y, acc);
    acc = fmaf(bf2f(xr[(size_t)(k + 2) * 64]), w.z, acc);
    acc = fmaf(bf2f(xr[(size_t)(k + 3) * 64]), w.w, acc);
  }
  #pragma unroll 2
  for (int k = 0; k < FEATD; k += 4) {
    float4 w = *(const float4*)(wr + HID + k);
    acc = fmaf(bf2f(cr[(size_t)(k + 0) * 64]), w.x, acc);
    acc = fmaf(bf2f(cr[(size_t)(k + 1) * 64]), w.y, acc);
    acc = fmaf(bf2f(cr[(size_t)(k + 2) * 64]), w.z, acc);
    acc = fmaf(bf2f(cr[(size_t)(k + 3) * 64]), w.w, acc);
  }
  fcl[lane * 8 + wv] = fmaxf(acc, 0.f);
  __syncthreads();
  const int b = tid >> 3, i = tid & 7;
  outp[((size_t)tp * BATCH + b) * OUTD + obase + i] = fcl[tid];   // 32B chunks
}

// ---------------- persistent per-speaker decoder ----------------
__global__ void __launch_bounds__(NTHR)
decoder_kernel(const float* __restrict__ hin, const float* __restrict__ u,
               const float* __restrict__ Wih0, const float* __restrict__ Wihr,
               const float* __restrict__ Wfc, const float* __restrict__ bfc,
               const float* __restrict__ c0, const float* __restrict__ hhT,
               float* __restrict__ s,
               ushort16* __restrict__ cB4, ushort16* __restrict__ x1B4,
               ushort16* __restrict__ x2B4,
               ushort16* __restrict__ chistK, ushort16* __restrict__ xhistK,
               unsigned* __restrict__ bar, float* __restrict__ outp)
{
  __shared__ ushort16 wlds[40960];   // 80 KB: B[0,8192) C[8192,24576) D[24576,40960)
  __shared__ float s_l[HID];
  __shared__ float e_l[64];
  __shared__ float a_l[64];
  __shared__ float red[2 * 4 * 16 * 16];
  __shared__ float fcl[512];

  const int tid  = threadIdx.x;
  const int bid  = blockIdx.x;
  const int wv   = tid >> 6;
  const int lane = tid & 63;

  // ---- one-time: swizzle this block's weight slice into LDS (bf16 A-frags) ----
  for (int r = tid; r < 40960; r += NTHR) {
    int local, ksz; const float* Wsrc;
    if (r < 8192)        { local = r;         ksz = FEATD; Wsrc = Wih0; }
    else if (r < 24576)  { local = r - 8192;  ksz = HID;   Wsrc = Wihr; }
    else                 { local = r - 24576; ksz = HID;   Wsrc = Wihr + (size_t)G4H * HID; }
    const int ks   = local >> 9;
    const int li   = local & 511;
    const int ln   = li >> 3;
    const int jj   = li & 7;
    const int m    = ln & 15;
    const int quad = ln >> 4;
    const int k    = ks * 32 + quad * 8 + jj;
    const int n    = (m >> 2) * HID + (bid << 2) + (m & 3);
    wlds[r] = f2bf(Wsrc[(size_t)n * ksz + k]);
  }
  __syncthreads();

  for (int t = 0; t < T_LEN; ++t) {
    const int slot = t & 15;
    // ---- Stage A: attention (blocks 0..63) / FC bursts (blocks 64..255, every 3rd) ----
    if (bid < BATCH) {
      const int b = bid;
      s_l[tid]        = s[(size_t)b * HID + tid];
      s_l[tid + NTHR] = s[(size_t)b * HID + tid + NTHR];
      __syncthreads();
      for (int w = wv; w < WLEN; w += 8) {
        const int tau = t + w - WINR;
        float e = 0.f;   // zero-padded window -> e=0 participates in softmax
        if (tau >= 0 && tau < T_LEN) {
          const float* up = u + ((size_t)tau * BATCH + b) * HID;
          #pragma unroll
          for (int i = 0; i < 16; ++i) {
            const int hidx = lane + (i << 6);
            e += s_l[hidx] * up[hidx];
          }
          #pragma unroll
          for (int m = 32; m; m >>= 1) e += __shfl_xor(e, m);
        }
        if (lane == 0) e_l[w] = e;
      }
      __syncthreads();
      if (tid < 64) {
        float e = (tid < WLEN) ? e_l[tid] : -1e30f;
        float mx = e;
        #pragma unroll
        for (int m = 32; m; m >>= 1) mx = fmaxf(mx, __shfl_xor(mx, m));
        float p = (tid < WLEN) ? expf(e - mx) : 0.f;
        float sm = p;
        #pragma unroll
        for (int m = 32; m; m >>= 1) sm += __shfl_xor(sm, m);
        if (tid < WLEN) a_l[tid] = p / sm;
      }
      __syncthreads();
      {
        float c = 0.f;
        for (int w = 0; w < WLEN; ++w) {
          const int tau = t + w - WINR;
          if (tau >= 0 && tau < T_LEN)
            c = fmaf(a_l[w], hin[((size_t)tau * BATCH + b) * FEATD + tid], c);
        }
        ushort16 cb = f2bf(c);
        cB4[((size_t)(tid >> 2) * 64 + b) * 4 + (tid & 3)] = cb;      // MFMA layout
        chistK[((size_t)slot * FEATD + tid) * 64 + b] = cb;           // FC layout
      }
    } else if (t >= 3 && t % 3 == 0) {
      const int fb  = bid - BATCH;          // 0..191
      const int tp  = t - 3 + (fb >> 6);    // 3 timesteps x 64 blocks
      const int obase = (fb & 63) << 3;
      fc_step(tp, obase, chistK, xhistK, Wfc, bfc, outp, fcl);
    }
    grid_barrier(bar);
    // ---- Stages B/C/D ----
    lstm_stage_mfma<16>(wlds, cB4, hhT, c0,
                        x1B4, nullptr, nullptr, red);
    grid_barrier(bar);
    lstm_stage_mfma<32>(wlds + 8192, x1B4, hhT + (size_t)G4H * 64,
                        c0 + (size_t)BATCH * HID, x2B4, nullptr, nullptr, red);
    grid_barrier(bar);
    lstm_stage_mfma<32>(wlds + 24576, x2B4, hhT + (size_t)2 * G4H * 64,
                        c0 + (size_t)2 * BATCH * HID, nullptr,
                        xhistK + (size_t)slot * HID * 64, s, red);
    grid_barrier(bar);
  }
  // ---- epilogue: FC for tp = 510, 511 on blocks 0..127 ----
  if (bid < 128) {
    const int tp = 510 + (bid >> 6);
    const int obase = (bid & 63) << 3;
    fc_step(tp, obase, chistK, xhistK, Wfc, bfc, outp, fcl);
  }
}

// ---------------- u = h @ Wa_sp^T : [32768,512] x [1024,512]^T (fp32) ----------------
__global__ void __launch_bounds__(256)
gemm_u_kernel(const float* __restrict__ A, const float* __restrict__ Bm,
              float* __restrict__ C)
{
  __shared__ float Al[64 * 68];
  __shared__ float Bl[64 * 68];
  const int tid = threadIdx.x;
  const int m0 = blockIdx.x * 64;
  const int n0 = blockIdx.y * 64;
  const int tx = tid & 15, ty = tid >> 4;
  float acc[4][4] = {};
  for (int kc = 0; kc < 512; kc += 64) {
    #pragma unroll
    for (int p = 0; p < 4; ++p) {
      const int row = p * 16 + (tid >> 4);
      const int kq  = (tid & 15) * 4;
      float4 v = *(const float4*)(A + (size_t)(m0 + row) * 512 + kc + kq);
      Al[(kq + 0) * 68 + row] = v.x;
      Al[(kq + 1) * 68 + row] = v.y;
      Al[(kq + 2) * 68 + row] = v.z;
      Al[(kq + 3) * 68 + row] = v.w;
      float4 w = *(const float4*)(Bm + (size_t)(n0 + row) * 512 + kc + kq);
      Bl[(kq + 0) * 68 + row] = w.x;
      Bl[(kq + 1) * 68 + row] = w.y;
      Bl[(kq + 2) * 68 + row] = w.z;
      Bl[(kq + 3) * 68 + row] = w.w;
    }
    __syncthreads();
    #pragma unroll 8
    for (int k = 0; k < 64; ++k) {
      float4 av = *(const float4*)(&Al[k * 68 + ty * 4]);
      float4 bv = *(const float4*)(&Bl[k * 68 + tx * 4]);
      float aa[4] = {av.x, av.y, av.z, av.w};
      float bb[4] = {bv.x, bv.y, bv.z, bv.w};
      #pragma unroll
      for (int i = 0; i < 4; ++i)
        #pragma unroll
        for (int jj = 0; jj < 4; ++jj)
          acc[i][jj] = fmaf(aa[i], bb[jj], acc[i][jj]);
    }
    __syncthreads();
  }
  #pragma unroll
  for (int i = 0; i < 4; ++i) {
    float4 r = {acc[i][0], acc[i][1], acc[i][2], acc[i][3]};
    *(float4*)(C + (size_t)(m0 + ty * 4 + i) * 1024 + n0 + tx * 4) = r;
  }
}

// ------- hhT[l][n][b] = h0[l,b,:] . Whh_l[n,:] + bih_l[n] + bhh_l[n] -------
__global__ void __launch_bounds__(256)
hhconst_kernel(const float* __restrict__ Whh0, const float* __restrict__ Whr,
               const float* __restrict__ bih0, const float* __restrict__ bhh0,
               const float* __restrict__ bihr, const float* __restrict__ bhhr,
               const float* __restrict__ h0, float* __restrict__ hh)
{
  const int idx = blockIdx.x * 256 + threadIdx.x;   // 786432 total
  const int b = idx & 63;
  const int n = (idx >> 6) & 4095;
  const int l = idx >> 18;
  const float* W = (l == 0) ? (Whh0 + (size_t)n * HID)
                            : (Whr + ((size_t)(l - 1) * G4H + n) * HID);
  float acc = ((l == 0) ? bih0[n] : bihr[(l - 1) * G4H + n])
            + ((l == 0) ? bhh0[n] : bhhr[(l - 1) * G4H + n]);
  const float* hr = h0 + ((size_t)l * BATCH + b) * HID;
  #pragma unroll 2
  for (int k = 0; k < HID; k += 4) {
    float4 a4 = *(const float4*)(hr + k);
    float4 w4 = *(const float4*)(W + k);
    acc += a4.x * w4.x + a4.y * w4.y + a4.z * w4.z + a4.w * w4.w;
  }
  hh[idx] = acc;    // (l*G4H + n)*64 + b  -> k-major, coalesced
}

__global__ void __launch_bounds__(256)
init_kernel(const float* __restrict__ s0, float* __restrict__ s, unsigned* __restrict__ bar)
{
  const int gid = blockIdx.x * 256 + threadIdx.x;
  if (gid < BATCH * HID) s[gid] = s0[gid];
  if (blockIdx.x == 0)
    for (int i = threadIdx.x; i < 1024; i += 256) bar[i] = 0u;
}

extern "C" void kernel_launch(void* const* d_in, const int* in_sizes, int n_in,
                              void* d_out, int out_size, void* d_ws, size_t ws_size,
                              hipStream_t stream) {
  (void)in_sizes; (void)n_in; (void)out_size; (void)ws_size;
  const float* h    = (const float*)d_in[0];
  const float* Wa   = (const float*)d_in[1];
  const float* Wih0 = (const float*)d_in[2];
  const float* Whh0 = (const float*)d_in[3];
  const float* bih0 = (const float*)d_in[4];
  const float* bhh0 = (const float*)d_in[5];
  const float* Wihr = (const float*)d_in[6];
  const float* Whhr = (const float*)d_in[7];
  const float* bihr = (const float*)d_in[8];
  const float* bhhr = (const float*)d_in[9];
  const float* Wfc  = (const float*)d_in[10];
  const float* bfc  = (const float*)d_in[11];
  const float* s0   = (const float*)d_in[12];
  const float* h0   = (const float*)d_in[13];
  const float* c0   = (const float*)d_in[14];
  float* out = (float*)d_out;
  float* ws  = (float*)d_ws;

  float* u        = ws + OFF_U;
  float* hhT      = ws + OFF_HH;
  float* s        = ws + OFF_S;
  ushort16* cB4   = (ushort16*)(ws + OFF_CB);
  ushort16* x1B4  = (ushort16*)(ws + OFF_X1);
  ushort16* x2B4  = (ushort16*)(ws + OFF_X2);
  ushort16* chistK= (ushort16*)(ws + OFF_CK);
  ushort16* xhistK= (ushort16*)(ws + OFF_XK);
  unsigned* bar   = (unsigned*)(ws + OFF_BAR);

  hipLaunchKernelGGL(init_kernel, dim3(256), dim3(256), 0, stream, s0, s, bar);
  hipLaunchKernelGGL(hhconst_kernel, dim3(3072), dim3(256), 0, stream,
                     Whh0, Whhr, bih0, bhh0, bihr, bhhr, h0, hhT);
  for (int sp = 0; sp < 2; ++sp) {
    hipLaunchKernelGGL(gemm_u_kernel, dim3(512, 16), dim3(256), 0, stream,
                       h, Wa + (size_t)sp * HID * FEATD, u);
    hipLaunchKernelGGL(decoder_kernel, dim3(NBLK), dim3(NTHR), 0, stream,
                       h, u, Wih0, Wihr, Wfc, bfc, c0, hhT, s,
                       cB4, x1B4, x2B4, chistK, xhistK, bar,
                       out + (size_t)sp * T_LEN * BATCH * OUTD);
  }
}